// Round 3
// baseline (136.688 us; speedup 1.0000x reference)
//
#include <hip/hip_runtime.h>
#include <math.h>

#define NN 2048
#define CC 128
#define ROWS 16      // batch rows per block
#define EPSF 1e-16f

__device__ __forceinline__ float wave_sum(float v) {
#pragma unroll
  for (int o = 32; o; o >>= 1) v += __shfl_xor(v, o, 64);
  return v;
}
__device__ __forceinline__ float softplusf(float x) {
  return fmaxf(x, 0.0f) + log1pf(__expf(-fabsf(x)));
}

// ---- transpose M[2048][128] -> Mt4[c4][n] (float4-granular) ----
__global__ __launch_bounds__(256) void ntm_transpose_kernel(
    const float4* __restrict__ M4, float4* __restrict__ Mt4) {
  const int t = threadIdx.x;
  const int n = blockIdx.x * 32 + (t & 31);
  const int c4b = t >> 5;  // 0..7
#pragma unroll
  for (int i = 0; i < 4; ++i) {
    const int c4 = c4b + 8 * i;
    Mt4[c4 * NN + n] = M4[n * 32 + c4];
  }
}

template <bool USE_MT>
__global__ __launch_bounds__(1024, 1) void ntm_main_kernel(
    const float* __restrict__ kptr, const float* __restrict__ beta_,
    const float* __restrict__ g_, const float* __restrict__ s_,
    const float* __restrict__ gamma_, const float* __restrict__ w_prev,
    const float* __restrict__ M, const float4* __restrict__ Mt4,
    float* __restrict__ out) {
  __shared__ float red[ROWS][16];       // [row][wave] partial sums
  __shared__ float edges[ROWS][16][2];  // [row][wave][first,last] w_g values

  const int t = threadIdx.x;
  const int lane = t & 63;
  const int w = __builtin_amdgcn_readfirstlane(t >> 6);  // 0..15, uniform
  const int b0 = blockIdx.x * ROWS;
  const int nbase = 128 * w + lane;  // n for li=0 ; li=1 is +64
  const int lanem1 = (lane + 63) & 63;
  const int lanep1 = (lane + 1) & 63;

  // ---------------- phase 1: dot products + M row norms ----------------
  float v[ROWS][2];  // acc -> exp -> w_g -> w_sharp (renamed through phases)
  float msq0 = 0.f, msq1 = 0.f;
#pragma unroll
  for (int r = 0; r < ROWS; ++r) { v[r][0] = 0.f; v[r][1] = 0.f; }

  const float4* M4 = (const float4*)M;
#pragma unroll 4
  for (int c4 = 0; c4 < 32; ++c4) {
    float4 m0, m1;
    if (USE_MT) {
      m0 = Mt4[c4 * NN + nbase];
      m1 = Mt4[c4 * NN + nbase + 64];
    } else {
      m0 = M4[nbase * 32 + c4];
      m1 = M4[(nbase + 64) * 32 + c4];
    }
    msq0 += m0.x * m0.x + m0.y * m0.y + m0.z * m0.z + m0.w * m0.w;
    msq1 += m1.x * m1.x + m1.y * m1.y + m1.z * m1.z + m1.w * m1.w;
#pragma unroll
    for (int r = 0; r < ROWS; ++r) {
      // uniform address -> s_load_dwordx4, SGPR operands in the FMAs
      float4 kv = *(const float4*)&kptr[(b0 + r) * CC + 4 * c4];
      v[r][0] += kv.x * m0.x + kv.y * m0.y + kv.z * m0.z + kv.w * m0.w;
      v[r][1] += kv.x * m1.x + kv.y * m1.y + kv.z * m1.z + kv.w * m1.w;
    }
  }
  const float im0 = 1.0f / sqrtf(msq0);  // 1/||M[n0]||
  const float im1 = 1.0f / sqrtf(msq1);  // 1/||M[n0+64]||

  // k row norms (each wave computes all 16, redundant but cheap)
  float kinv[ROWS];
#pragma unroll
  for (int r = 0; r < ROWS; ++r) {
    float2 kv = *(const float2*)&kptr[(b0 + r) * CC + 2 * lane];
    kinv[r] = 1.0f / sqrtf(wave_sum(kv.x * kv.x + kv.y * kv.y));
  }

  // ---------------- phase 2a: logits -> exp -> local sums ----------------
  // |beta*sim| <= ~5, so exp() needs no max subtraction.
#pragma unroll
  for (int r = 0; r < ROWS; ++r) {
    const float zb = softplusf(beta_[b0 + r]) * kinv[r];
    float e0 = __expf(v[r][0] * zb * im0);
    float e1 = __expf(v[r][1] * zb * im1);
    v[r][0] = e0;
    v[r][1] = e1;
    float sl = wave_sum(e0 + e1);
    if (lane == 0) red[r][w] = sl;
  }
  __syncthreads();  // B1

  // ---------------- phase 2b: normalize, gate, write slab edges ----------
#pragma unroll
  for (int r = 0; r < ROWS; ++r) {
    float4 s0v = *(const float4*)&red[r][0];
    float4 s1v = *(const float4*)&red[r][4];
    float4 s2v = *(const float4*)&red[r][8];
    float4 s3v = *(const float4*)&red[r][12];
    float tot = (s0v.x + s0v.y + s0v.z + s0v.w) + (s1v.x + s1v.y + s1v.z + s1v.w) +
                (s2v.x + s2v.y + s2v.z + s2v.w) + (s3v.x + s3v.y + s3v.z + s3v.w);
    const float einv = 1.0f / tot;
    const float gv = 1.0f / (1.0f + __expf(-g_[b0 + r]));
    const size_t base = (size_t)(b0 + r) * NN + nbase;
    float wp0 = w_prev[base];
    float wp1 = w_prev[base + 64];
    float wg0 = gv * (v[r][0] * einv) + (1.0f - gv) * wp0;
    float wg1 = gv * (v[r][1] * einv) + (1.0f - gv) * wp1;
    v[r][0] = wg0;
    v[r][1] = wg1;
    if (lane == 0) edges[r][w][0] = wg0;   // n = 128w (slab first)
    if (lane == 63) edges[r][w][1] = wg1;  // n = 128w+127 (slab last)
  }
  __syncthreads();  // B2

  // ---------------- phase 2c: circular conv + sharpen + local sums -------
#pragma unroll
  for (int r = 0; r < ROWS; ++r) {
    float sh0 = s_[3 * (b0 + r)], sh1 = s_[3 * (b0 + r) + 1], sh2 = s_[3 * (b0 + r) + 2];
    float shm = fmaxf(sh0, fmaxf(sh1, sh2));
    float e0 = __expf(sh0 - shm), e1 = __expf(sh1 - shm), e2 = __expf(sh2 - shm);
    float sden = 1.0f / (e0 + e1 + e2);
    sh0 = e0 * sden; sh1 = e1 * sden; sh2 = e2 * sden;
    const float gammav = 1.0f + softplusf(gamma_[b0 + r]);

    const float eL = edges[r][(w + 15) & 15][1];  // w_g[n-1] for slab start
    const float eR = edges[r][(w + 1) & 15][0];   // w_g[n+1] for slab end
    const float w0 = v[r][0], w1 = v[r][1];
    const float sh_w0_m = __shfl(w0, lanem1, 64);
    const float sh_w0_p = __shfl(w0, lanep1, 64);
    const float sh_w1_m = __shfl(w1, lanem1, 64);
    const float sh_w1_p = __shfl(w1, lanep1, 64);
    float p0 = (lane == 0) ? eL : sh_w0_m;
    float n0 = (lane == 63) ? sh_w1_p : sh_w0_p;  // lane63: w1 from lane0 = n+1
    float p1 = (lane == 0) ? sh_w0_m : sh_w1_m;   // lane0: w0 from lane63 = n-1
    float n1 = (lane == 63) ? eR : sh_w1_p;
    float wt0 = sh0 * p0 + sh1 * w0 + sh2 * n0;
    float wt1 = sh0 * p1 + sh1 * w1 + sh2 * n1;
    float q0 = __expf(gammav * __logf(wt0));
    float q1 = __expf(gammav * __logf(wt1));
    v[r][0] = q0;
    v[r][1] = q1;
    float sl = wave_sum(q0 + q1);
    if (lane == 0) red[r][w] = sl;
  }
  __syncthreads();  // B3

  // ---------------- phase 2d: final normalize + store --------------------
#pragma unroll
  for (int r = 0; r < ROWS; ++r) {
    float4 s0v = *(const float4*)&red[r][0];
    float4 s1v = *(const float4*)&red[r][4];
    float4 s2v = *(const float4*)&red[r][8];
    float4 s3v = *(const float4*)&red[r][12];
    float tot = (s0v.x + s0v.y + s0v.z + s0v.w) + (s1v.x + s1v.y + s1v.z + s1v.w) +
                (s2v.x + s2v.y + s2v.z + s2v.w) + (s3v.x + s3v.y + s3v.z + s3v.w);
    const float pinv = 1.0f / (tot + EPSF);
    const size_t base = (size_t)(b0 + r) * NN + nbase;
    out[base] = v[r][0] * pinv;
    out[base + 64] = v[r][1] * pinv;
  }
}

extern "C" void kernel_launch(void* const* d_in, const int* in_sizes, int n_in,
                              void* d_out, int out_size, void* d_ws, size_t ws_size,
                              hipStream_t stream) {
  const float* k = (const float*)d_in[0];
  const float* beta = (const float*)d_in[1];
  const float* g = (const float*)d_in[2];
  const float* s = (const float*)d_in[3];
  const float* gamma = (const float*)d_in[4];
  const float* w_prev = (const float*)d_in[5];
  const float* M = (const float*)d_in[6];
  float* out = (float*)d_out;

  const size_t mt_bytes = (size_t)CC * NN * sizeof(float);  // 1 MiB
  if (ws_size >= mt_bytes) {
    float4* Mt4 = (float4*)d_ws;
    ntm_transpose_kernel<<<NN / 32, 256, 0, stream>>>((const float4*)M, Mt4);
    ntm_main_kernel<true><<<4096 / ROWS, 1024, 0, stream>>>(
        k, beta, g, s, gamma, w_prev, M, Mt4, out);
  } else {
    ntm_main_kernel<false><<<4096 / ROWS, 1024, 0, stream>>>(
        k, beta, g, s, gamma, w_prev, M, nullptr, out);
  }
}

// Round 4
// 60.682 us; speedup vs baseline: 2.2525x; 2.2525x over previous
//
#include <hip/hip_runtime.h>
#include <math.h>

#define NN 2048
#define CC 128
#define ROWS 16
#define EPSF 1e-16f

typedef __attribute__((ext_vector_type(8))) short bf16x8;
typedef __attribute__((ext_vector_type(4))) float f32x4;

__device__ __forceinline__ float softplusf(float x) {
  return fmaxf(x, 0.0f) + log1pf(__expf(-fabsf(x)));
}

union U8 { uint u[4]; bf16x8 v; };

// split 8 fp32 into bf16 hi (truncate) + bf16 lo (residual, truncate),
// packed for MFMA; also accumulate sum of squares of the originals.
__device__ __forceinline__ void split8(float4 a, float4 b, bf16x8& hi,
                                       bf16x8& lo, float& sq) {
  float f[8] = {a.x, a.y, a.z, a.w, b.x, b.y, b.z, b.w};
  U8 H, L;
#pragma unroll
  for (int i = 0; i < 4; ++i) {
    float f0 = f[2 * i], f1 = f[2 * i + 1];
    sq += f0 * f0;
    sq += f1 * f1;
    uint u0 = __float_as_uint(f0), u1 = __float_as_uint(f1);
    uint m0 = u0 & 0xffff0000u, m1 = u1 & 0xffff0000u;
    float r0 = f0 - __uint_as_float(m0);
    float r1 = f1 - __uint_as_float(m1);
    H.u[i] = (u0 >> 16) | m1;
    L.u[i] = (__float_as_uint(r0) >> 16) | (__float_as_uint(r1) & 0xffff0000u);
  }
  hi = H.v;
  lo = L.v;
}

__global__ __launch_bounds__(1024) void ntm_main_kernel(
    const float* __restrict__ kptr, const float* __restrict__ beta_,
    const float* __restrict__ g_, const float* __restrict__ s_,
    const float* __restrict__ gamma_, const float* __restrict__ w_prev,
    const float* __restrict__ Mptr, float* __restrict__ out) {
  __shared__ float red[ROWS][16];       // [row][wave] partial sums
  __shared__ float edges[ROWS][16][2];  // [row][wave][first,last] w_g

  const int t = threadIdx.x;
  const int lane = t & 63;
  const int w = __builtin_amdgcn_readfirstlane(t >> 6);  // 0..15
  const int l15 = lane & 15;
  const int lg = lane >> 4;  // 0..3
  const int b0 = blockIdx.x * ROWS;

  // ---- A fragments (k rows) + k row norms ----
  // lane l: A[row=l15][kk=lg*8+j] for kstep ks -> k[b0+l15][ks*32+lg*8+j]
  const float* kr = kptr + (b0 + l15) * CC + lg * 8;
  bf16x8 ah[4], al[4];
  float ksq = 0.f;
#pragma unroll
  for (int ks = 0; ks < 4; ++ks) {
    float4 a0 = *(const float4*)(kr + ks * 32);
    float4 a1 = *(const float4*)(kr + ks * 32 + 4);
    split8(a0, a1, ah[ks], al[ks], ksq);
  }
  ksq += __shfl_xor(ksq, 16, 64);
  ksq += __shfl_xor(ksq, 32, 64);
  const float ikn_own = 1.0f / sqrtf(ksq);  // 1/||k[b0+l15]||

  // ---- MFMA: 8 column tiles of 16, split-bf16 (3 products) ----
  f32x4 accT[8];
  float imn[8];
#pragma unroll
  for (int tt = 0; tt < 8; ++tt) {
    const int n0t = 128 * w + 16 * tt;
    const float* mr = Mptr + (size_t)(n0t + l15) * CC + lg * 8;
    f32x4 acc = {0.f, 0.f, 0.f, 0.f};
    float msq = 0.f;
#pragma unroll
    for (int ks = 0; ks < 4; ++ks) {
      float4 m0 = *(const float4*)(mr + ks * 32);
      float4 m1 = *(const float4*)(mr + ks * 32 + 4);
      bf16x8 bh, bl;
      split8(m0, m1, bh, bl, msq);
      acc = __builtin_amdgcn_mfma_f32_16x16x32_bf16(ah[ks], bh, acc, 0, 0, 0);
      acc = __builtin_amdgcn_mfma_f32_16x16x32_bf16(al[ks], bh, acc, 0, 0, 0);
      acc = __builtin_amdgcn_mfma_f32_16x16x32_bf16(ah[ks], bl, acc, 0, 0, 0);
    }
    msq += __shfl_xor(msq, 16, 64);
    msq += __shfl_xor(msq, 32, 64);
    imn[tt] = 1.0f / sqrtf(msq);  // 1/||M[n0t+l15]||
    accT[tt] = acc;
  }
  // D layout: col(n) = n0t + l15 ; row(batch) = lg*4 + q  (q = vector comp)

  // ---- phase 2a: logits -> exp -> per-wave row sums ----
#pragma unroll
  for (int q = 0; q < 4; ++q) {
    const int rr = lg * 4 + q;
    const float zb = softplusf(beta_[b0 + rr]) * __shfl(ikn_own, rr, 64);
    float rs = 0.f;
#pragma unroll
    for (int tt = 0; tt < 8; ++tt) {
      float e = __expf(accT[tt][q] * imn[tt] * zb);  // |logit| <= ~5
      accT[tt][q] = e;
      rs += e;
    }
    rs += __shfl_xor(rs, 1, 64);
    rs += __shfl_xor(rs, 2, 64);
    rs += __shfl_xor(rs, 4, 64);
    rs += __shfl_xor(rs, 8, 64);
    if (l15 == 0) red[rr][w] = rs;
  }
  __syncthreads();  // B1

  // ---- phase 2b: softmax-normalize, gate with w_prev, write slab edges ----
#pragma unroll
  for (int q = 0; q < 4; ++q) {
    const int rr = lg * 4 + q;
    float4 p0 = *(const float4*)&red[rr][0];
    float4 p1 = *(const float4*)&red[rr][4];
    float4 p2 = *(const float4*)&red[rr][8];
    float4 p3 = *(const float4*)&red[rr][12];
    float tot = (p0.x + p0.y + p0.z + p0.w) + (p1.x + p1.y + p1.z + p1.w) +
                (p2.x + p2.y + p2.z + p2.w) + (p3.x + p3.y + p3.z + p3.w);
    const float gv = 1.0f / (1.0f + __expf(-g_[b0 + rr]));
    const float ge = gv / tot;
    const float om = 1.0f - gv;
    const size_t rbase = (size_t)(b0 + rr) * NN + 128 * w + l15;
#pragma unroll
    for (int tt = 0; tt < 8; ++tt) {
      float wp = w_prev[rbase + 16 * tt];
      accT[tt][q] = ge * accT[tt][q] + om * wp;
    }
    if (l15 == 0) edges[rr][w][0] = accT[0][q];
    if (l15 == 15) edges[rr][w][1] = accT[7][q];
  }
  __syncthreads();  // B2

  // ---- phase 2c: circular conv (in-group shuffles) + sharpen + row sums ----
  const int tm = (lane & 48) | ((lane + 15) & 15);
  const int tp = (lane & 48) | ((lane + 1) & 15);
#pragma unroll
  for (int q = 0; q < 4; ++q) {
    const int rr = lg * 4 + q;
    float sh0 = s_[3 * (b0 + rr)];
    float sh1 = s_[3 * (b0 + rr) + 1];
    float sh2 = s_[3 * (b0 + rr) + 2];
    float shm = fmaxf(sh0, fmaxf(sh1, sh2));
    float e0 = __expf(sh0 - shm), e1 = __expf(sh1 - shm), e2 = __expf(sh2 - shm);
    float sden = 1.0f / (e0 + e1 + e2);
    sh0 = e0 * sden; sh1 = e1 * sden; sh2 = e2 * sden;
    const float gammav = 1.0f + softplusf(gamma_[b0 + rr]);
    const float eL = edges[rr][(w + 15) & 15][1];  // w_g[n-1] at slab start
    const float eR = edges[rr][(w + 1) & 15][0];   // w_g[n+1] at slab end

    float sm[8], sp[8];
#pragma unroll
    for (int tt = 0; tt < 8; ++tt) {
      sm[tt] = __shfl(accT[tt][q], tm, 64);
      sp[tt] = __shfl(accT[tt][q], tp, 64);
    }
    float rs = 0.f;
#pragma unroll
    for (int tt = 0; tt < 8; ++tt) {
      float pv = (l15 == 0) ? ((tt == 0) ? eL : sm[tt - 1]) : sm[tt];
      float nx = (l15 == 15) ? ((tt == 7) ? eR : sp[tt + 1]) : sp[tt];
      float wt = sh0 * pv + sh1 * accT[tt][q] + sh2 * nx;
      float p = __expf(gammav * __logf(wt));  // wt^gamma ; wt>0
      accT[tt][q] = p;
      rs += p;
    }
    rs += __shfl_xor(rs, 1, 64);
    rs += __shfl_xor(rs, 2, 64);
    rs += __shfl_xor(rs, 4, 64);
    rs += __shfl_xor(rs, 8, 64);
    if (l15 == 0) red[rr][w] = rs;
  }
  __syncthreads();  // B3

  // ---- phase 2d: final normalize + store ----
#pragma unroll
  for (int q = 0; q < 4; ++q) {
    const int rr = lg * 4 + q;
    float4 p0 = *(const float4*)&red[rr][0];
    float4 p1 = *(const float4*)&red[rr][4];
    float4 p2 = *(const float4*)&red[rr][8];
    float4 p3 = *(const float4*)&red[rr][12];
    float tot = (p0.x + p0.y + p0.z + p0.w) + (p1.x + p1.y + p1.z + p1.w) +
                (p2.x + p2.y + p2.z + p2.w) + (p3.x + p3.y + p3.z + p3.w);
    const float pinv = 1.0f / (tot + EPSF);
    const size_t rbase = (size_t)(b0 + rr) * NN + 128 * w + l15;
#pragma unroll
    for (int tt = 0; tt < 8; ++tt) {
      out[rbase + 16 * tt] = accT[tt][q] * pinv;
    }
  }
}

extern "C" void kernel_launch(void* const* d_in, const int* in_sizes, int n_in,
                              void* d_out, int out_size, void* d_ws, size_t ws_size,
                              hipStream_t stream) {
  const float* k = (const float*)d_in[0];
  const float* beta = (const float*)d_in[1];
  const float* g = (const float*)d_in[2];
  const float* s = (const float*)d_in[3];
  const float* gamma = (const float*)d_in[4];
  const float* w_prev = (const float*)d_in[5];
  const float* M = (const float*)d_in[6];
  float* out = (float*)d_out;

  ntm_main_kernel<<<4096 / ROWS, 1024, 0, stream>>>(k, beta, g, s, gamma,
                                                    w_prev, M, out);
}

// Round 5
// 43.280 us; speedup vs baseline: 3.1582x; 1.4021x over previous
//
#include <hip/hip_runtime.h>
#include <math.h>

#define NN 2048
#define CC 128
#define ROWS 16
#define EPSF 1e-16f

typedef __attribute__((ext_vector_type(8))) short bf16x8;
typedef __attribute__((ext_vector_type(4))) float f32x4;

__device__ __forceinline__ float softplusf(float x) {
  return fmaxf(x, 0.0f) + log1pf(__expf(-fabsf(x)));
}

union U8 { uint u[4]; bf16x8 v; };

// split 8 fp32 into bf16 hi (truncate) + bf16 lo (residual, truncate),
// packed for MFMA; also accumulate sum of squares of the originals.
__device__ __forceinline__ void split8(float4 a, float4 b, bf16x8& hi,
                                       bf16x8& lo, float& sq) {
  float f[8] = {a.x, a.y, a.z, a.w, b.x, b.y, b.z, b.w};
  U8 H, L;
#pragma unroll
  for (int i = 0; i < 4; ++i) {
    float f0 = f[2 * i], f1 = f[2 * i + 1];
    sq += f0 * f0;
    sq += f1 * f1;
    uint u0 = __float_as_uint(f0), u1 = __float_as_uint(f1);
    uint m0 = u0 & 0xffff0000u, m1 = u1 & 0xffff0000u;
    float r0 = f0 - __uint_as_float(m0);
    float r1 = f1 - __uint_as_float(m1);
    H.u[i] = (u0 >> 16) | m1;
    L.u[i] = (__float_as_uint(r0) >> 16) | (__float_as_uint(r1) & 0xffff0000u);
  }
  hi = H.v;
  lo = L.v;
}

// ---------------- prep: split M and k into frag-ordered bf16 hi/lo, ----
// ---------------- row norms, and per-row activation scalars ------------
__global__ __launch_bounds__(256) void ntm_prep_kernel(
    const float* __restrict__ kptr, const float* __restrict__ beta_,
    const float* __restrict__ g_, const float* __restrict__ s_,
    const float* __restrict__ gamma_, const float* __restrict__ M,
    bf16x8* __restrict__ Mhf, bf16x8* __restrict__ Mlf,
    bf16x8* __restrict__ Khf, bf16x8* __restrict__ Klf,
    float* __restrict__ imn, float* __restrict__ zb, float* __restrict__ gvv,
    float* __restrict__ gmv, float* __restrict__ s0a, float* __restrict__ s1a,
    float* __restrict__ s2a) {
  const int bid = blockIdx.x;
  const int t = threadIdx.x;
  if (bid < 96) {
    const int lane = t & 63;
    const int wv = t >> 6;
    const int l15 = lane & 15;
    const int lg = lane >> 4;
    const bool isM = bid < 32;
    const int grp = (isM ? bid : bid - 32) * 4 + wv;  // M: 0..127, K: 0..255
    const float* src = (isM ? M : kptr) + (grp * 16 + l15) * CC + lg * 8;
    bf16x8* dh = (isM ? Mhf : Khf) + (grp * 4) * 64 + lane;
    bf16x8* dl = (isM ? Mlf : Klf) + (grp * 4) * 64 + lane;
    float sq = 0.f;
#pragma unroll
    for (int ks = 0; ks < 4; ++ks) {
      float4 a0 = *(const float4*)(src + ks * 32);
      float4 a1 = *(const float4*)(src + ks * 32 + 4);
      bf16x8 h, l;
      split8(a0, a1, h, l, sq);
      dh[ks * 64] = h;
      dl[ks * 64] = l;
    }
    sq += __shfl_xor(sq, 16, 64);
    sq += __shfl_xor(sq, 32, 64);
    if (lg == 0) {
      const int row = grp * 16 + l15;
      if (isM) {
        imn[row] = 1.0f / sqrtf(sq);
      } else {
        zb[row] = softplusf(beta_[row]) / sqrtf(sq);  // beta * (1/||k||)
      }
    }
  } else {
    const int r = (bid - 96) * 256 + t;  // 0..4095
    gvv[r] = 1.0f / (1.0f + __expf(-g_[r]));
    gmv[r] = 1.0f + softplusf(gamma_[r]);
    float sh0 = s_[3 * r], sh1 = s_[3 * r + 1], sh2 = s_[3 * r + 2];
    float shm = fmaxf(sh0, fmaxf(sh1, sh2));
    float e0 = __expf(sh0 - shm), e1 = __expf(sh1 - shm), e2 = __expf(sh2 - shm);
    float sden = 1.0f / (e0 + e1 + e2);
    s0a[r] = e0 * sden;
    s1a[r] = e1 * sden;
    s2a[r] = e2 * sden;
  }
}

// ---------------- main: MFMA matmul + fused softmax/gate/conv/sharpen ----
__global__ __launch_bounds__(1024) void ntm_main_kernel(
    const float* __restrict__ w_prev, const bf16x8* __restrict__ Mhf,
    const bf16x8* __restrict__ Mlf, const bf16x8* __restrict__ Khf,
    const bf16x8* __restrict__ Klf, const float* __restrict__ imn,
    const float* __restrict__ zb, const float* __restrict__ gvv,
    const float* __restrict__ gmv, const float* __restrict__ s0a,
    const float* __restrict__ s1a, const float* __restrict__ s2a,
    float* __restrict__ out) {
  __shared__ float red[ROWS][16];       // [row][wave] partial sums
  __shared__ float edges[ROWS][16][2];  // [row][wave][first,last] w_g

  const int t = threadIdx.x;
  const int lane = t & 63;
  const int w = __builtin_amdgcn_readfirstlane(t >> 6);  // 0..15
  const int l15 = lane & 15;
  const int lg = lane >> 4;  // 0..3
  const int bg = blockIdx.x;
  const int b0 = bg * ROWS;

  // ---- A fragments (k rows), precomputed ----
  bf16x8 ah[4], al[4];
#pragma unroll
  for (int ks = 0; ks < 4; ++ks) {
    ah[ks] = Khf[(bg * 4 + ks) * 64 + lane];
    al[ks] = Klf[(bg * 4 + ks) * 64 + lane];
  }

  // ---- MFMA: 8 column tiles of 16, split-bf16 (3 products) ----
  f32x4 accT[8];
  float imn_t[8];
#pragma unroll
  for (int tt = 0; tt < 8; ++tt) {
    const int gM = 8 * w + tt;  // M row-group (16 rows each)
    f32x4 acc = {0.f, 0.f, 0.f, 0.f};
#pragma unroll
    for (int ks = 0; ks < 4; ++ks) {
      bf16x8 bh = Mhf[(gM * 4 + ks) * 64 + lane];
      bf16x8 bl = Mlf[(gM * 4 + ks) * 64 + lane];
      acc = __builtin_amdgcn_mfma_f32_16x16x32_bf16(ah[ks], bh, acc, 0, 0, 0);
      acc = __builtin_amdgcn_mfma_f32_16x16x32_bf16(al[ks], bh, acc, 0, 0, 0);
      acc = __builtin_amdgcn_mfma_f32_16x16x32_bf16(ah[ks], bl, acc, 0, 0, 0);
    }
    accT[tt] = acc;
    imn_t[tt] = imn[128 * w + 16 * tt + l15];
  }
  // D layout: col(n) = 128w + 16tt + l15 ; row(batch) = lg*4 + q

  // ---- phase 2a: logits -> exp -> per-wave row sums ----
#pragma unroll
  for (int q = 0; q < 4; ++q) {
    const int rr = lg * 4 + q;
    const float zbv = zb[b0 + rr];
    float rs = 0.f;
#pragma unroll
    for (int tt = 0; tt < 8; ++tt) {
      float e = __expf(accT[tt][q] * imn_t[tt] * zbv);  // |logit| <= ~5
      accT[tt][q] = e;
      rs += e;
    }
    rs += __shfl_xor(rs, 1, 64);
    rs += __shfl_xor(rs, 2, 64);
    rs += __shfl_xor(rs, 4, 64);
    rs += __shfl_xor(rs, 8, 64);
    if (l15 == 0) red[rr][w] = rs;
  }
  __syncthreads();  // B1

  // ---- phase 2b: softmax-normalize, gate with w_prev, write slab edges ----
#pragma unroll
  for (int q = 0; q < 4; ++q) {
    const int rr = lg * 4 + q;
    float4 p0 = *(const float4*)&red[rr][0];
    float4 p1 = *(const float4*)&red[rr][4];
    float4 p2 = *(const float4*)&red[rr][8];
    float4 p3 = *(const float4*)&red[rr][12];
    float tot = (p0.x + p0.y + p0.z + p0.w) + (p1.x + p1.y + p1.z + p1.w) +
                (p2.x + p2.y + p2.z + p2.w) + (p3.x + p3.y + p3.z + p3.w);
    const float gv = gvv[b0 + rr];
    const float ge = gv / tot;
    const float om = 1.0f - gv;
    const size_t rbase = (size_t)(b0 + rr) * NN + 128 * w + l15;
#pragma unroll
    for (int tt = 0; tt < 8; ++tt) {
      float wp = w_prev[rbase + 16 * tt];
      accT[tt][q] = ge * accT[tt][q] + om * wp;
    }
    if (l15 == 0) edges[rr][w][0] = accT[0][q];
    if (l15 == 15) edges[rr][w][1] = accT[7][q];
  }
  __syncthreads();  // B2

  // ---- phase 2c: circular conv (in-group shuffles) + sharpen + row sums ----
  const int tm = (lane & 48) | ((lane + 15) & 15);
  const int tp = (lane & 48) | ((lane + 1) & 15);
#pragma unroll
  for (int q = 0; q < 4; ++q) {
    const int rr = lg * 4 + q;
    const float sh0 = s0a[b0 + rr];
    const float sh1 = s1a[b0 + rr];
    const float sh2 = s2a[b0 + rr];
    const float gammav = gmv[b0 + rr];
    const float eL = edges[rr][(w + 15) & 15][1];  // w_g[n-1] at slab start
    const float eR = edges[rr][(w + 1) & 15][0];   // w_g[n+1] at slab end

    float sm[8], sp[8];
#pragma unroll
    for (int tt = 0; tt < 8; ++tt) {
      sm[tt] = __shfl(accT[tt][q], tm, 64);
      sp[tt] = __shfl(accT[tt][q], tp, 64);
    }
    float rs = 0.f;
#pragma unroll
    for (int tt = 0; tt < 8; ++tt) {
      float pv = (l15 == 0) ? ((tt == 0) ? eL : sm[tt - 1]) : sm[tt];
      float nx = (l15 == 15) ? ((tt == 7) ? eR : sp[tt + 1]) : sp[tt];
      float wt = sh0 * pv + sh1 * accT[tt][q] + sh2 * nx;
      float p = __expf(gammav * __logf(wt));  // wt^gamma ; wt>0
      accT[tt][q] = p;
      rs += p;
    }
    rs += __shfl_xor(rs, 1, 64);
    rs += __shfl_xor(rs, 2, 64);
    rs += __shfl_xor(rs, 4, 64);
    rs += __shfl_xor(rs, 8, 64);
    if (l15 == 0) red[rr][w] = rs;
  }
  __syncthreads();  // B3

  // ---- phase 2d: final normalize + store ----
#pragma unroll
  for (int q = 0; q < 4; ++q) {
    const int rr = lg * 4 + q;
    float4 p0 = *(const float4*)&red[rr][0];
    float4 p1 = *(const float4*)&red[rr][4];
    float4 p2 = *(const float4*)&red[rr][8];
    float4 p3 = *(const float4*)&red[rr][12];
    float tot = (p0.x + p0.y + p0.z + p0.w) + (p1.x + p1.y + p1.z + p1.w) +
                (p2.x + p2.y + p2.z + p2.w) + (p3.x + p3.y + p3.z + p3.w);
    const float pinv = 1.0f / (tot + EPSF);
    const size_t rbase = (size_t)(b0 + rr) * NN + 128 * w + l15;
#pragma unroll
    for (int tt = 0; tt < 8; ++tt) {
      out[rbase + 16 * tt] = accT[tt][q] * pinv;
    }
  }
}

// ---------------- fallback (round-4 kernel, no workspace) ----------------
__global__ __launch_bounds__(1024) void ntm_main_fallback(
    const float* __restrict__ kptr, const float* __restrict__ beta_,
    const float* __restrict__ g_, const float* __restrict__ s_,
    const float* __restrict__ gamma_, const float* __restrict__ w_prev,
    const float* __restrict__ Mptr, float* __restrict__ out) {
  __shared__ float red[ROWS][16];
  __shared__ float edges[ROWS][16][2];
  const int t = threadIdx.x;
  const int lane = t & 63;
  const int w = __builtin_amdgcn_readfirstlane(t >> 6);
  const int l15 = lane & 15;
  const int lg = lane >> 4;
  const int b0 = blockIdx.x * ROWS;

  const float* kr = kptr + (b0 + l15) * CC + lg * 8;
  bf16x8 ah[4], al[4];
  float ksq = 0.f;
#pragma unroll
  for (int ks = 0; ks < 4; ++ks) {
    float4 a0 = *(const float4*)(kr + ks * 32);
    float4 a1 = *(const float4*)(kr + ks * 32 + 4);
    split8(a0, a1, ah[ks], al[ks], ksq);
  }
  ksq += __shfl_xor(ksq, 16, 64);
  ksq += __shfl_xor(ksq, 32, 64);
  const float ikn_own = 1.0f / sqrtf(ksq);

  f32x4 accT[8];
  float imn[8];
#pragma unroll
  for (int tt = 0; tt < 8; ++tt) {
    const int n0t = 128 * w + 16 * tt;
    const float* mr = Mptr + (size_t)(n0t + l15) * CC + lg * 8;
    f32x4 acc = {0.f, 0.f, 0.f, 0.f};
    float msq = 0.f;
#pragma unroll
    for (int ks = 0; ks < 4; ++ks) {
      float4 m0 = *(const float4*)(mr + ks * 32);
      float4 m1 = *(const float4*)(mr + ks * 32 + 4);
      bf16x8 bh, bl;
      split8(m0, m1, bh, bl, msq);
      acc = __builtin_amdgcn_mfma_f32_16x16x32_bf16(ah[ks], bh, acc, 0, 0, 0);
      acc = __builtin_amdgcn_mfma_f32_16x16x32_bf16(al[ks], bh, acc, 0, 0, 0);
      acc = __builtin_amdgcn_mfma_f32_16x16x32_bf16(ah[ks], bl, acc, 0, 0, 0);
    }
    msq += __shfl_xor(msq, 16, 64);
    msq += __shfl_xor(msq, 32, 64);
    imn[tt] = 1.0f / sqrtf(msq);
    accT[tt] = acc;
  }

#pragma unroll
  for (int q = 0; q < 4; ++q) {
    const int rr = lg * 4 + q;
    const float zb = softplusf(beta_[b0 + rr]) * __shfl(ikn_own, rr, 64);
    float rs = 0.f;
#pragma unroll
    for (int tt = 0; tt < 8; ++tt) {
      float e = __expf(accT[tt][q] * imn[tt] * zb);
      accT[tt][q] = e;
      rs += e;
    }
    rs += __shfl_xor(rs, 1, 64);
    rs += __shfl_xor(rs, 2, 64);
    rs += __shfl_xor(rs, 4, 64);
    rs += __shfl_xor(rs, 8, 64);
    if (l15 == 0) red[rr][w] = rs;
  }
  __syncthreads();

#pragma unroll
  for (int q = 0; q < 4; ++q) {
    const int rr = lg * 4 + q;
    float4 p0 = *(const float4*)&red[rr][0];
    float4 p1 = *(const float4*)&red[rr][4];
    float4 p2 = *(const float4*)&red[rr][8];
    float4 p3 = *(const float4*)&red[rr][12];
    float tot = (p0.x + p0.y + p0.z + p0.w) + (p1.x + p1.y + p1.z + p1.w) +
                (p2.x + p2.y + p2.z + p2.w) + (p3.x + p3.y + p3.z + p3.w);
    const float gv = 1.0f / (1.0f + __expf(-g_[b0 + rr]));
    const float ge = gv / tot;
    const float om = 1.0f - gv;
    const size_t rbase = (size_t)(b0 + rr) * NN + 128 * w + l15;
#pragma unroll
    for (int tt = 0; tt < 8; ++tt) {
      float wp = w_prev[rbase + 16 * tt];
      accT[tt][q] = ge * accT[tt][q] + om * wp;
    }
    if (l15 == 0) edges[rr][w][0] = accT[0][q];
    if (l15 == 15) edges[rr][w][1] = accT[7][q];
  }
  __syncthreads();

  const int tm = (lane & 48) | ((lane + 15) & 15);
  const int tp = (lane & 48) | ((lane + 1) & 15);
#pragma unroll
  for (int q = 0; q < 4; ++q) {
    const int rr = lg * 4 + q;
    float sh0 = s_[3 * (b0 + rr)];
    float sh1 = s_[3 * (b0 + rr) + 1];
    float sh2 = s_[3 * (b0 + rr) + 2];
    float shm = fmaxf(sh0, fmaxf(sh1, sh2));
    float e0 = __expf(sh0 - shm), e1 = __expf(sh1 - shm), e2 = __expf(sh2 - shm);
    float sden = 1.0f / (e0 + e1 + e2);
    sh0 = e0 * sden; sh1 = e1 * sden; sh2 = e2 * sden;
    const float gammav = 1.0f + softplusf(gamma_[b0 + rr]);
    const float eL = edges[rr][(w + 15) & 15][1];
    const float eR = edges[rr][(w + 1) & 15][0];
    float sm[8], sp[8];
#pragma unroll
    for (int tt = 0; tt < 8; ++tt) {
      sm[tt] = __shfl(accT[tt][q], tm, 64);
      sp[tt] = __shfl(accT[tt][q], tp, 64);
    }
    float rs = 0.f;
#pragma unroll
    for (int tt = 0; tt < 8; ++tt) {
      float pv = (l15 == 0) ? ((tt == 0) ? eL : sm[tt - 1]) : sm[tt];
      float nx = (l15 == 15) ? ((tt == 7) ? eR : sp[tt + 1]) : sp[tt];
      float wt = sh0 * pv + sh1 * accT[tt][q] + sh2 * nx;
      float p = __expf(gammav * __logf(wt));
      accT[tt][q] = p;
      rs += p;
    }
    rs += __shfl_xor(rs, 1, 64);
    rs += __shfl_xor(rs, 2, 64);
    rs += __shfl_xor(rs, 4, 64);
    rs += __shfl_xor(rs, 8, 64);
    if (l15 == 0) red[rr][w] = rs;
  }
  __syncthreads();

#pragma unroll
  for (int q = 0; q < 4; ++q) {
    const int rr = lg * 4 + q;
    float4 p0 = *(const float4*)&red[rr][0];
    float4 p1 = *(const float4*)&red[rr][4];
    float4 p2 = *(const float4*)&red[rr][8];
    float4 p3 = *(const float4*)&red[rr][12];
    float tot = (p0.x + p0.y + p0.z + p0.w) + (p1.x + p1.y + p1.z + p1.w) +
                (p2.x + p2.y + p2.z + p2.w) + (p3.x + p3.y + p3.z + p3.w);
    const float pinv = 1.0f / (tot + EPSF);
    const size_t rbase = (size_t)(b0 + rr) * NN + 128 * w + l15;
#pragma unroll
    for (int tt = 0; tt < 8; ++tt) {
      out[rbase + 16 * tt] = accT[tt][q] * pinv;
    }
  }
}

extern "C" void kernel_launch(void* const* d_in, const int* in_sizes, int n_in,
                              void* d_out, int out_size, void* d_ws, size_t ws_size,
                              hipStream_t stream) {
  const float* k = (const float*)d_in[0];
  const float* beta = (const float*)d_in[1];
  const float* g = (const float*)d_in[2];
  const float* s = (const float*)d_in[3];
  const float* gamma = (const float*)d_in[4];
  const float* w_prev = (const float*)d_in[5];
  const float* M = (const float*)d_in[6];
  float* out = (float*)d_out;

  // workspace layout (bytes)
  char* ws = (char*)d_ws;
  bf16x8* Mhf = (bf16x8*)(ws + 0);        // 512 KB (128 grp * 4 ks * 64 ln)
  bf16x8* Mlf = (bf16x8*)(ws + 524288);   // 512 KB
  bf16x8* Khf = (bf16x8*)(ws + 1048576);  // 1 MB (256 grp)
  bf16x8* Klf = (bf16x8*)(ws + 2097152);  // 1 MB
  float* imn = (float*)(ws + 3145728);    // 2048
  float* zb = imn + 2048;                 // 4096
  float* gvv = zb + 4096;
  float* gmv = gvv + 4096;
  float* s0a = gmv + 4096;
  float* s1a = s0a + 4096;
  float* s2a = s1a + 4096;
  const size_t need = 3145728 + 2048 * 4 + 6 * 4096 * 4;

  if (ws_size >= need) {
    ntm_prep_kernel<<<112, 256, 0, stream>>>(k, beta, g, s, gamma, M, Mhf, Mlf,
                                             Khf, Klf, imn, zb, gvv, gmv, s0a,
                                             s1a, s2a);
    ntm_main_kernel<<<4096 / ROWS, 1024, 0, stream>>>(
        w_prev, Mhf, Mlf, Khf, Klf, imn, zb, gvv, gmv, s0a, s1a, s2a, out);
  } else {
    ntm_main_fallback<<<4096 / ROWS, 1024, 0, stream>>>(k, beta, g, s, gamma,
                                                        w_prev, M, out);
  }
}

// Round 6
// 42.595 us; speedup vs baseline: 3.2090x; 1.0161x over previous
//
#include <hip/hip_runtime.h>
#include <math.h>

#define NN 2048
#define CC 128
#define ROWS 16
#define EPSF 1e-16f

typedef __attribute__((ext_vector_type(8))) short bf16x8;
typedef __attribute__((ext_vector_type(4))) float f32x4;

__device__ __forceinline__ float softplusf(float x) {
  return fmaxf(x, 0.0f) + log1pf(__expf(-fabsf(x)));
}

union U8 { uint u[4]; bf16x8 v; };

// split 8 fp32 into bf16 hi (truncate) + bf16 lo (residual, truncate),
// packed for MFMA; also accumulate sum of squares of the originals.
__device__ __forceinline__ void split8(float4 a, float4 b, bf16x8& hi,
                                       bf16x8& lo, float& sq) {
  float f[8] = {a.x, a.y, a.z, a.w, b.x, b.y, b.z, b.w};
  U8 H, L;
#pragma unroll
  for (int i = 0; i < 4; ++i) {
    float f0 = f[2 * i], f1 = f[2 * i + 1];
    sq += f0 * f0;
    sq += f1 * f1;
    uint u0 = __float_as_uint(f0), u1 = __float_as_uint(f1);
    uint m0 = u0 & 0xffff0000u, m1 = u1 & 0xffff0000u;
    float r0 = f0 - __uint_as_float(m0);
    float r1 = f1 - __uint_as_float(m1);
    H.u[i] = (u0 >> 16) | m1;
    L.u[i] = (__float_as_uint(r0) >> 16) | (__float_as_uint(r1) & 0xffff0000u);
  }
  hi = H.v;
  lo = L.v;
}

// ---------------- prep: split M and k into frag-ordered bf16 hi/lo, ----
// ---------------- row norms, and per-row activation scalars ------------
__global__ __launch_bounds__(256) void ntm_prep_kernel(
    const float* __restrict__ kptr, const float* __restrict__ beta_,
    const float* __restrict__ g_, const float* __restrict__ s_,
    const float* __restrict__ gamma_, const float* __restrict__ M,
    bf16x8* __restrict__ Mhf, bf16x8* __restrict__ Mlf,
    bf16x8* __restrict__ Khf, bf16x8* __restrict__ Klf,
    float* __restrict__ imn, float* __restrict__ zb, float* __restrict__ gvv,
    float* __restrict__ gmv, float* __restrict__ s0a, float* __restrict__ s1a,
    float* __restrict__ s2a) {
  const int bid = blockIdx.x;
  const int t = threadIdx.x;
  if (bid < 96) {
    const int lane = t & 63;
    const int wv = t >> 6;
    const int l15 = lane & 15;
    const int lg = lane >> 4;
    const bool isM = bid < 32;
    const int grp = (isM ? bid : bid - 32) * 4 + wv;  // M: 0..127, K: 0..255
    const float* src = (isM ? M : kptr) + (grp * 16 + l15) * CC + lg * 8;
    bf16x8* dh = (isM ? Mhf : Khf) + (grp * 4) * 64 + lane;
    bf16x8* dl = (isM ? Mlf : Klf) + (grp * 4) * 64 + lane;
    float sq = 0.f;
#pragma unroll
    for (int ks = 0; ks < 4; ++ks) {
      float4 a0 = *(const float4*)(src + ks * 32);
      float4 a1 = *(const float4*)(src + ks * 32 + 4);
      bf16x8 h, l;
      split8(a0, a1, h, l, sq);
      dh[ks * 64] = h;
      dl[ks * 64] = l;
    }
    sq += __shfl_xor(sq, 16, 64);
    sq += __shfl_xor(sq, 32, 64);
    if (lg == 0) {
      const int row = grp * 16 + l15;
      if (isM) {
        imn[row] = 1.0f / sqrtf(sq);
      } else {
        zb[row] = softplusf(beta_[row]) / sqrtf(sq);  // beta * (1/||k||)
      }
    }
  } else {
    const int r = (bid - 96) * 256 + t;  // 0..4095
    gvv[r] = 1.0f / (1.0f + __expf(-g_[r]));
    gmv[r] = 1.0f + softplusf(gamma_[r]);
    float sh0 = s_[3 * r], sh1 = s_[3 * r + 1], sh2 = s_[3 * r + 2];
    float shm = fmaxf(sh0, fmaxf(sh1, sh2));
    float e0 = __expf(sh0 - shm), e1 = __expf(sh1 - shm), e2 = __expf(sh2 - shm);
    float sden = 1.0f / (e0 + e1 + e2);
    s0a[r] = e0 * sden;
    s1a[r] = e1 * sden;
    s2a[r] = e2 * sden;
  }
}

// ---------------- main: MFMA matmul + fused softmax/gate/conv/sharpen ----
__global__ __launch_bounds__(1024) void ntm_main_kernel(
    const float* __restrict__ w_prev, const bf16x8* __restrict__ Mhf,
    const bf16x8* __restrict__ Mlf, const bf16x8* __restrict__ Khf,
    const bf16x8* __restrict__ Klf, const float* __restrict__ imn,
    const float* __restrict__ zb, const float* __restrict__ gvv,
    const float* __restrict__ gmv, const float* __restrict__ s0a,
    const float* __restrict__ s1a, const float* __restrict__ s2a,
    float* __restrict__ out) {
  __shared__ float red[ROWS][16];       // [row][wave] partial sums
  __shared__ float edges[ROWS][16][2];  // [row][wave][first,last] w_g

  const int t = threadIdx.x;
  const int lane = t & 63;
  const int w = __builtin_amdgcn_readfirstlane(t >> 6);  // 0..15
  const int l15 = lane & 15;
  const int lg = lane >> 4;  // 0..3
  const int bg = blockIdx.x;
  const int b0 = bg * ROWS;

  // ---- MFMA: ks-outer, tt-inner; 16 B-frag loads hoisted per ks for MLP ----
  f32x4 accT[8];
#pragma unroll
  for (int tt = 0; tt < 8; ++tt) accT[tt] = (f32x4){0.f, 0.f, 0.f, 0.f};

#pragma unroll
  for (int ks = 0; ks < 4; ++ks) {
    bf16x8 bh[8], bl[8];
#pragma unroll
    for (int tt = 0; tt < 8; ++tt) {
      const int gM = 8 * w + tt;  // M row-group (16 rows each)
      bh[tt] = Mhf[(gM * 4 + ks) * 64 + lane];
      bl[tt] = Mlf[(gM * 4 + ks) * 64 + lane];
    }
    const bf16x8 ah = Khf[(bg * 4 + ks) * 64 + lane];
    const bf16x8 al = Klf[(bg * 4 + ks) * 64 + lane];
#pragma unroll
    for (int tt = 0; tt < 8; ++tt) {
      accT[tt] = __builtin_amdgcn_mfma_f32_16x16x32_bf16(ah, bh[tt], accT[tt], 0, 0, 0);
      accT[tt] = __builtin_amdgcn_mfma_f32_16x16x32_bf16(al, bh[tt], accT[tt], 0, 0, 0);
      accT[tt] = __builtin_amdgcn_mfma_f32_16x16x32_bf16(ah, bl[tt], accT[tt], 0, 0, 0);
    }
  }
  // D layout: col(n) = 128w + 16tt + l15 ; row(batch) = lg*4 + q

  // ---- T14 prefetch: w_prev + per-row/col scalars, issued before phase 2a,
  // ---- consumed after B1 (latency hides under exp/reduction + MFMA drain) ----
  float wp[4][8];
#pragma unroll
  for (int q = 0; q < 4; ++q) {
    const size_t rbase = (size_t)(b0 + lg * 4 + q) * NN + 128 * w + l15;
#pragma unroll
    for (int tt = 0; tt < 8; ++tt) wp[q][tt] = w_prev[rbase + 16 * tt];
  }
  float imn_t[8];
#pragma unroll
  for (int tt = 0; tt < 8; ++tt) imn_t[tt] = imn[128 * w + 16 * tt + l15];
  float zbv[4], gvq[4];
#pragma unroll
  for (int q = 0; q < 4; ++q) {
    zbv[q] = zb[b0 + lg * 4 + q];
    gvq[q] = gvv[b0 + lg * 4 + q];
  }

  // ---- phase 2a: logits -> exp -> per-wave row sums ----
#pragma unroll
  for (int q = 0; q < 4; ++q) {
    const int rr = lg * 4 + q;
    float rs = 0.f;
#pragma unroll
    for (int tt = 0; tt < 8; ++tt) {
      float e = __expf(accT[tt][q] * imn_t[tt] * zbv[q]);  // |logit| <= ~5
      accT[tt][q] = e;
      rs += e;
    }
    rs += __shfl_xor(rs, 1, 64);
    rs += __shfl_xor(rs, 2, 64);
    rs += __shfl_xor(rs, 4, 64);
    rs += __shfl_xor(rs, 8, 64);
    if (l15 == 0) red[rr][w] = rs;
  }
  __syncthreads();  // B1

  // ---- phase 2b: softmax-normalize, gate with w_prev, write slab edges ----
#pragma unroll
  for (int q = 0; q < 4; ++q) {
    const int rr = lg * 4 + q;
    float4 p0 = *(const float4*)&red[rr][0];
    float4 p1 = *(const float4*)&red[rr][4];
    float4 p2 = *(const float4*)&red[rr][8];
    float4 p3 = *(const float4*)&red[rr][12];
    float tot = (p0.x + p0.y + p0.z + p0.w) + (p1.x + p1.y + p1.z + p1.w) +
                (p2.x + p2.y + p2.z + p2.w) + (p3.x + p3.y + p3.z + p3.w);
    const float gv = gvq[q];
    const float ge = gv / tot;
    const float om = 1.0f - gv;
#pragma unroll
    for (int tt = 0; tt < 8; ++tt) {
      accT[tt][q] = ge * accT[tt][q] + om * wp[q][tt];
    }
    if (l15 == 0) edges[rr][w][0] = accT[0][q];
    if (l15 == 15) edges[rr][w][1] = accT[7][q];
  }
  __syncthreads();  // B2

  // ---- phase 2c: circular conv (in-group shuffles) + sharpen + row sums ----
  const int tm = (lane & 48) | ((lane + 15) & 15);
  const int tp = (lane & 48) | ((lane + 1) & 15);
#pragma unroll
  for (int q = 0; q < 4; ++q) {
    const int rr = lg * 4 + q;
    const float sh0 = s0a[b0 + rr];
    const float sh1 = s1a[b0 + rr];
    const float sh2 = s2a[b0 + rr];
    const float gammav = gmv[b0 + rr];
    const float eL = edges[rr][(w + 15) & 15][1];  // w_g[n-1] at slab start
    const float eR = edges[rr][(w + 1) & 15][0];   // w_g[n+1] at slab end

    float sm[8], sp[8];
#pragma unroll
    for (int tt = 0; tt < 8; ++tt) {
      sm[tt] = __shfl(accT[tt][q], tm, 64);
      sp[tt] = __shfl(accT[tt][q], tp, 64);
    }
    float rs = 0.f;
#pragma unroll
    for (int tt = 0; tt < 8; ++tt) {
      float pv = (l15 == 0) ? ((tt == 0) ? eL : sm[tt - 1]) : sm[tt];
      float nx = (l15 == 15) ? ((tt == 7) ? eR : sp[tt + 1]) : sp[tt];
      float wt = sh0 * pv + sh1 * accT[tt][q] + sh2 * nx;
      float p = __expf(gammav * __logf(wt));  // wt^gamma ; wt>0
      accT[tt][q] = p;
      rs += p;
    }
    rs += __shfl_xor(rs, 1, 64);
    rs += __shfl_xor(rs, 2, 64);
    rs += __shfl_xor(rs, 4, 64);
    rs += __shfl_xor(rs, 8, 64);
    if (l15 == 0) red[rr][w] = rs;
  }
  __syncthreads();  // B3

  // ---- phase 2d: final normalize + store ----
#pragma unroll
  for (int q = 0; q < 4; ++q) {
    const int rr = lg * 4 + q;
    float4 p0 = *(const float4*)&red[rr][0];
    float4 p1 = *(const float4*)&red[rr][4];
    float4 p2 = *(const float4*)&red[rr][8];
    float4 p3 = *(const float4*)&red[rr][12];
    float tot = (p0.x + p0.y + p0.z + p0.w) + (p1.x + p1.y + p1.z + p1.w) +
                (p2.x + p2.y + p2.z + p2.w) + (p3.x + p3.y + p3.z + p3.w);
    const float pinv = 1.0f / (tot + EPSF);
    const size_t rbase = (size_t)(b0 + rr) * NN + 128 * w + l15;
#pragma unroll
    for (int tt = 0; tt < 8; ++tt) {
      out[rbase + 16 * tt] = accT[tt][q] * pinv;
    }
  }
}

// ---------------- fallback (round-4 kernel, no workspace) ----------------
__global__ __launch_bounds__(1024) void ntm_main_fallback(
    const float* __restrict__ kptr, const float* __restrict__ beta_,
    const float* __restrict__ g_, const float* __restrict__ s_,
    const float* __restrict__ gamma_, const float* __restrict__ w_prev,
    const float* __restrict__ Mptr, float* __restrict__ out) {
  __shared__ float red[ROWS][16];
  __shared__ float edges[ROWS][16][2];
  const int t = threadIdx.x;
  const int lane = t & 63;
  const int w = __builtin_amdgcn_readfirstlane(t >> 6);
  const int l15 = lane & 15;
  const int lg = lane >> 4;
  const int b0 = blockIdx.x * ROWS;

  const float* kr = kptr + (b0 + l15) * CC + lg * 8;
  bf16x8 ah[4], al[4];
  float ksq = 0.f;
#pragma unroll
  for (int ks = 0; ks < 4; ++ks) {
    float4 a0 = *(const float4*)(kr + ks * 32);
    float4 a1 = *(const float4*)(kr + ks * 32 + 4);
    split8(a0, a1, ah[ks], al[ks], ksq);
  }
  ksq += __shfl_xor(ksq, 16, 64);
  ksq += __shfl_xor(ksq, 32, 64);
  const float ikn_own = 1.0f / sqrtf(ksq);

  f32x4 accT[8];
  float imn[8];
#pragma unroll
  for (int tt = 0; tt < 8; ++tt) {
    const int n0t = 128 * w + 16 * tt;
    const float* mr = Mptr + (size_t)(n0t + l15) * CC + lg * 8;
    f32x4 acc = {0.f, 0.f, 0.f, 0.f};
    float msq = 0.f;
#pragma unroll
    for (int ks = 0; ks < 4; ++ks) {
      float4 m0 = *(const float4*)(mr + ks * 32);
      float4 m1 = *(const float4*)(mr + ks * 32 + 4);
      bf16x8 bh, bl;
      split8(m0, m1, bh, bl, msq);
      acc = __builtin_amdgcn_mfma_f32_16x16x32_bf16(ah[ks], bh, acc, 0, 0, 0);
      acc = __builtin_amdgcn_mfma_f32_16x16x32_bf16(al[ks], bh, acc, 0, 0, 0);
      acc = __builtin_amdgcn_mfma_f32_16x16x32_bf16(ah[ks], bl, acc, 0, 0, 0);
    }
    msq += __shfl_xor(msq, 16, 64);
    msq += __shfl_xor(msq, 32, 64);
    imn[tt] = 1.0f / sqrtf(msq);
    accT[tt] = acc;
  }

#pragma unroll
  for (int q = 0; q < 4; ++q) {
    const int rr = lg * 4 + q;
    const float zb = softplusf(beta_[b0 + rr]) * __shfl(ikn_own, rr, 64);
    float rs = 0.f;
#pragma unroll
    for (int tt = 0; tt < 8; ++tt) {
      float e = __expf(accT[tt][q] * imn[tt] * zb);
      accT[tt][q] = e;
      rs += e;
    }
    rs += __shfl_xor(rs, 1, 64);
    rs += __shfl_xor(rs, 2, 64);
    rs += __shfl_xor(rs, 4, 64);
    rs += __shfl_xor(rs, 8, 64);
    if (l15 == 0) red[rr][w] = rs;
  }
  __syncthreads();

#pragma unroll
  for (int q = 0; q < 4; ++q) {
    const int rr = lg * 4 + q;
    float4 p0 = *(const float4*)&red[rr][0];
    float4 p1 = *(const float4*)&red[rr][4];
    float4 p2 = *(const float4*)&red[rr][8];
    float4 p3 = *(const float4*)&red[rr][12];
    float tot = (p0.x + p0.y + p0.z + p0.w) + (p1.x + p1.y + p1.z + p1.w) +
                (p2.x + p2.y + p2.z + p2.w) + (p3.x + p3.y + p3.z + p3.w);
    const float gv = 1.0f / (1.0f + __expf(-g_[b0 + rr]));
    const float ge = gv / tot;
    const float om = 1.0f - gv;
    const size_t rbase = (size_t)(b0 + rr) * NN + 128 * w + l15;
#pragma unroll
    for (int tt = 0; tt < 8; ++tt) {
      float wpv = w_prev[rbase + 16 * tt];
      accT[tt][q] = ge * accT[tt][q] + om * wpv;
    }
    if (l15 == 0) edges[rr][w][0] = accT[0][q];
    if (l15 == 15) edges[rr][w][1] = accT[7][q];
  }
  __syncthreads();

  const int tm = (lane & 48) | ((lane + 15) & 15);
  const int tp = (lane & 48) | ((lane + 1) & 15);
#pragma unroll
  for (int q = 0; q < 4; ++q) {
    const int rr = lg * 4 + q;
    float sh0 = s_[3 * (b0 + rr)];
    float sh1 = s_[3 * (b0 + rr) + 1];
    float sh2 = s_[3 * (b0 + rr) + 2];
    float shm = fmaxf(sh0, fmaxf(sh1, sh2));
    float e0 = __expf(sh0 - shm), e1 = __expf(sh1 - shm), e2 = __expf(sh2 - shm);
    float sden = 1.0f / (e0 + e1 + e2);
    sh0 = e0 * sden; sh1 = e1 * sden; sh2 = e2 * sden;
    const float gammav = 1.0f + softplusf(gamma_[b0 + rr]);
    const float eL = edges[rr][(w + 15) & 15][1];
    const float eR = edges[rr][(w + 1) & 15][0];
    float sm[8], sp[8];
#pragma unroll
    for (int tt = 0; tt < 8; ++tt) {
      sm[tt] = __shfl(accT[tt][q], tm, 64);
      sp[tt] = __shfl(accT[tt][q], tp, 64);
    }
    float rs = 0.f;
#pragma unroll
    for (int tt = 0; tt < 8; ++tt) {
      float pv = (l15 == 0) ? ((tt == 0) ? eL : sm[tt - 1]) : sm[tt];
      float nx = (l15 == 15) ? ((tt == 7) ? eR : sp[tt + 1]) : sp[tt];
      float wt = sh0 * pv + sh1 * accT[tt][q] + sh2 * nx;
      float p = __expf(gammav * __logf(wt));
      accT[tt][q] = p;
      rs += p;
    }
    rs += __shfl_xor(rs, 1, 64);
    rs += __shfl_xor(rs, 2, 64);
    rs += __shfl_xor(rs, 4, 64);
    rs += __shfl_xor(rs, 8, 64);
    if (l15 == 0) red[rr][w] = rs;
  }
  __syncthreads();

#pragma unroll
  for (int q = 0; q < 4; ++q) {
    const int rr = lg * 4 + q;
    float4 p0 = *(const float4*)&red[rr][0];
    float4 p1 = *(const float4*)&red[rr][4];
    float4 p2 = *(const float4*)&red[rr][8];
    float4 p3 = *(const float4*)&red[rr][12];
    float tot = (p0.x + p0.y + p0.z + p0.w) + (p1.x + p1.y + p1.z + p1.w) +
                (p2.x + p2.y + p2.z + p2.w) + (p3.x + p3.y + p3.z + p3.w);
    const float pinv = 1.0f / (tot + EPSF);
    const size_t rbase = (size_t)(b0 + rr) * NN + 128 * w + l15;
#pragma unroll
    for (int tt = 0; tt < 8; ++tt) {
      out[rbase + 16 * tt] = accT[tt][q] * pinv;
    }
  }
}

extern "C" void kernel_launch(void* const* d_in, const int* in_sizes, int n_in,
                              void* d_out, int out_size, void* d_ws, size_t ws_size,
                              hipStream_t stream) {
  const float* k = (const float*)d_in[0];
  const float* beta = (const float*)d_in[1];
  const float* g = (const float*)d_in[2];
  const float* s = (const float*)d_in[3];
  const float* gamma = (const float*)d_in[4];
  const float* w_prev = (const float*)d_in[5];
  const float* M = (const float*)d_in[6];
  float* out = (float*)d_out;

  // workspace layout (bytes)
  char* ws = (char*)d_ws;
  bf16x8* Mhf = (bf16x8*)(ws + 0);        // 512 KB (128 grp * 4 ks * 64 ln)
  bf16x8* Mlf = (bf16x8*)(ws + 524288);   // 512 KB
  bf16x8* Khf = (bf16x8*)(ws + 1048576);  // 1 MB (256 grp)
  bf16x8* Klf = (bf16x8*)(ws + 2097152);  // 1 MB
  float* imn = (float*)(ws + 3145728);    // 2048
  float* zb = imn + 2048;                 // 4096
  float* gvv = zb + 4096;
  float* gmv = gvv + 4096;
  float* s0a = gmv + 4096;
  float* s1a = s0a + 4096;
  float* s2a = s1a + 4096;
  const size_t need = 3145728 + 2048 * 4 + 6 * 4096 * 4;

  if (ws_size >= need) {
    ntm_prep_kernel<<<112, 256, 0, stream>>>(k, beta, g, s, gamma, M, Mhf, Mlf,
                                             Khf, Klf, imn, zb, gvv, gmv, s0a,
                                             s1a, s2a);
    ntm_main_kernel<<<4096 / ROWS, 1024, 0, stream>>>(
        w_prev, Mhf, Mlf, Khf, Klf, imn, zb, gvv, gmv, s0a, s1a, s2a, out);
  } else {
    ntm_main_fallback<<<4096 / ROWS, 1024, 0, stream>>>(k, beta, g, s, gamma,
                                                        w_prev, M, out);
  }
}